// Round 16
// baseline (7692.335 us; speedup 1.0000x reference)
//
#include <hip/hip_runtime.h>

#define T_STEPS 512
#define BATCH   64
#define HID     1024
#define IN      256
#define NWG     64
#define UPW     16            // hidden units per WG (M = 64 gate rows)
#define REDW    4160          // 64*65 floats per wave slice (padded)
#define LDS_FLOATS (8*REDW + 512 + 16)   // red + hs_hi(2048B) + wfcs
#define LDS_BYTES  (LDS_FLOATS * 4)

typedef float  f32x4  __attribute__((ext_vector_type(4)));
typedef short  short8 __attribute__((ext_vector_type(8)));
typedef unsigned short ushort_t;
typedef unsigned int   uint_t;

#define WAITVM(N) asm volatile("s_waitcnt vmcnt(" #N ")" ::: "memory")
#define SB0() __builtin_amdgcn_sched_barrier(0)

// ---------------------------------------------------------------------------
__device__ __forceinline__ ushort_t bf16rn(float f) {
    uint_t u = __builtin_bit_cast(uint_t, f);
    u += 0x7fff + ((u >> 16) & 1);
    return (ushort_t)(u >> 16);
}
__device__ __forceinline__ float bf16f(ushort_t h) {
    return __builtin_bit_cast(float, (uint_t)h << 16);
}
__device__ __forceinline__ void conv8(float4 a, float4 b, short8& hi, short8& lo) {
    float v[8] = {a.x, a.y, a.z, a.w, b.x, b.y, b.z, b.w};
#pragma unroll
    for (int j = 0; j < 8; ++j) {
        ushort_t h = bf16rn(v[j]);
        ushort_t l = bf16rn(v[j] - bf16f(h));
        hi[j] = (short)h; lo[j] = (short)l;
    }
}
__device__ __forceinline__ f32x4 mfma16(short8 a, short8 b, f32x4 c) {
    return __builtin_amdgcn_mfma_f32_16x16x32_bf16(a, b, c, 0, 0, 0);
}
// L1/L2-bypass 16B load; data valid only after s_waitcnt vmcnt(0) + sched_barrier.
__device__ __forceinline__ short8 load_coh16(const void* p) {
    short8 r;
    asm volatile("global_load_dwordx4 %0, %1, off sc0 sc1" : "=v"(r) : "v"(p));
    return r;
}

struct Frag4 { short8 h[4]; };

__device__ __forceinline__ void issue_set(const char* bhi, Frag4& F) {
#pragma unroll
    for (int n = 0; n < 4; ++n)
        F.h[n] = load_coh16(bhi + n * 32768);
}

// ---------------------------------------------------------------------------
// out init (b_fc) + flag clear.  grid 128 x 256.
__global__ __launch_bounds__(256) void init_k(
    float* __restrict__ out, int* __restrict__ flags, const float* __restrict__ bfc)
{
    int i = blockIdx.x * 256 + threadIdx.x;
    if (i < BATCH * T_STEPS) out[i] = bfc[0];
    if (i < 256) flags[i] = 0;
}

// x[b][t][i] -> xhi/xlo [t][b][i] (bf16 hi + residual). grid 512, block 256.
__global__ __launch_bounds__(256) void xprep_k(
    const float* __restrict__ x, ushort_t* __restrict__ xhi, ushort_t* __restrict__ xlo)
{
    const int t = blockIdx.x, i = threadIdx.x;
    for (int b = 0; b < BATCH; ++b) {
        float v = x[((size_t)b * T_STEPS + t) * IN + i];
        ushort_t h = bf16rn(v);
        ushort_t l = bf16rn(v - bf16f(h));
        size_t o = ((size_t)t * BATCH + b) * IN + i;
        xhi[o] = h; xlo[o] = l;
    }
}

// ---------------------------------------------------------------------------
// Persistent fused LSTM, MFMA split-bf16 weights/x, single-plane bf16 h.
// grid 64, block 512 (8 waves). NWG=64/M=64: halves the per-step h broadcast
// vs R15 (8 MB/step). Per WG: 16 units = 64 gate rows = 4 row-tiles of 16.
// Wave wv owns h k-tiles {wv+8i} + x k-tile wv (R14 mapping). Weights as
// split-bf16 A-frags in registers (160 VGPRs); launch_bounds(512,1) gives a
// 512-VGPR budget so nothing spills. R14-proven skeleton: x MFMAs pre-spin
// -> wave0 spins on all 64 flags (one read) -> bar -> issue ALL 16 coherent
// h loads -> single vmcnt(0)+sched_barrier -> 128 h MFMAs -> red reduce
// (bar) -> epilogue (2 units/thread, static unroll) -> hs staging (bar) ->
// uniform tail: tid<64 h store -> ALL waves WAITVM(0) -> bar -> tid0
// release -> tid<64 FC atomicAdd.
// ---------------------------------------------------------------------------
__global__ __launch_bounds__(512, 1) void lstm_seq(
    const float* __restrict__ Whh, const float* __restrict__ Wih,
    const float* __restrict__ bih, const float* __restrict__ bhh,
    const float* __restrict__ Wfc,
    const ushort_t* __restrict__ xhi, const ushort_t* __restrict__ xlo,
    ushort_t* __restrict__ h_hi,  // [2][BATCH][HID] bf16
    float* __restrict__ out,      // [BATCH][T]
    int* __restrict__ flags)      // [NWG]
{
    extern __shared__ float smem[];
    float*    red   = smem;                               // [8][64][65]
    ushort_t* hs_hi = (ushort_t*)(smem + 8 * REDW);       // [64][16] ushort (2048 B)
    float*    wfcs  = smem + 8 * REDW + 512;              // [16]

    const int tid  = threadIdx.x;
    const int wg   = blockIdx.x;
    const int u0   = wg * UPW;
    const int lane = tid & 63;
    const int wv   = tid >> 6;        // wave 0..7
    const int col  = lane & 15;
    const int kg   = lane >> 4;       // 0..3

    // ---- one-time: A-fragments (weights, split bf16) into registers ----
    // m-tile m covers units u0+4m..u0+4m+3; h k-tiles kt = wv+8i; x: 32+wv.
    short8 aHi[4][5], aLo[4][5];
    {
        const size_t growB = (size_t)(col >> 2) * HID + u0 + (col & 3);
#pragma unroll
        for (int m = 0; m < 4; ++m) {
            const size_t grow = growB + m * 4;
#pragma unroll
            for (int i = 0; i < 5; ++i) {
                const int kt = (i < 4) ? (wv + 8 * i) : (32 + wv);
                const int k0 = 32 * kt + kg * 8;
                const float* wp = (i < 4) ? (Whh + grow * HID + k0)
                                          : (Wih + grow * IN + (k0 - 1024));
                float4 wa = *(const float4*)wp;
                float4 wb = *(const float4*)(wp + 4);
                conv8(wa, wb, aHi[m][i], aLo[m][i]);
            }
        }
    }
    if (tid < UPW) wfcs[tid] = Wfc[u0 + tid];

    const int hoff = col * 2048 + kg * 16;             // h plane [b][1024] bf16
    const int xoff = col * 512 + wv * 64 + kg * 16;    // x plane [b][256]  bf16
    const char* hhiB = (const char*)h_hi;

    // epilogue constants: thread owns (ui, b) for ui in {tid>>6, tid>>6 + 8}
    const int ui0 = tid >> 6;         // 0..7
    const int b_ep = tid & 63;
    float bias_r[2][4];
#pragma unroll
    for (int hf = 0; hf < 2; ++hf)
#pragma unroll
        for (int gi = 0; gi < 4; ++gi)
            bias_r[hf][gi] = bih[gi * HID + u0 + ui0 + hf * 8]
                           + bhh[gi * HID + u0 + ui0 + hf * 8];

    float c0 = 0.f, c1 = 0.f;
    __syncthreads();

    for (int t = 0; t < T_STEPS; ++t) {
        f32x4 acc[4][4];
#pragma unroll
        for (int m = 0; m < 4; ++m)
#pragma unroll
            for (int n = 0; n < 4; ++n) acc[m][n] = (f32x4)0.f;

        // ---- x part (independent of h; cached loads; pre-spin overlap) ----
        {
            const char* bh = (const char*)xhi + (size_t)t * 32768 + xoff;
            const char* bl = (const char*)xlo + (size_t)t * 32768 + xoff;
            short8 xh[4], xl[4];
#pragma unroll
            for (int n = 0; n < 4; ++n) {
                xh[n] = *(const short8*)(bh + n * 8192);
                xl[n] = *(const short8*)(bl + n * 8192);
            }
#pragma unroll
            for (int m = 0; m < 4; ++m)
#pragma unroll
                for (int n = 0; n < 4; ++n) {
                    acc[m][n] = mfma16(aHi[m][4], xh[n], acc[m][n]);
                    acc[m][n] = mfma16(aHi[m][4], xl[n], acc[m][n]);
                    acc[m][n] = mfma16(aLo[m][4], xh[n], acc[m][n]);
                }
        }

        // ---- h part: wave0 spins on all 64 flags, then all waves load ----
        if (t > 0) {
            if (wv == 0) {
                for (;;) {
                    int f = __hip_atomic_load(flags + lane, __ATOMIC_RELAXED, __HIP_MEMORY_SCOPE_AGENT);
                    if (__all(f >= t)) break;
                    __builtin_amdgcn_s_sleep(1);
                }
            }
            __syncthreads();

            const int buf = ((t - 1) & 1) * 131072;   // bytes per h buffer
            const char* bh = hhiB + buf + hoff;
            Frag4 S0, S1, S2, S3;
            issue_set(bh + (wv +  0) * 64, S0);
            issue_set(bh + (wv +  8) * 64, S1);
            issue_set(bh + (wv + 16) * 64, S2);
            issue_set(bh + (wv + 24) * 64, S3);
            WAITVM(0); SB0();     // all 16 landed; only now touch the frags
#pragma unroll
            for (int m = 0; m < 4; ++m)
#pragma unroll
                for (int n = 0; n < 4; ++n) {
                    acc[m][n] = mfma16(aHi[m][0], S0.h[n], acc[m][n]);
                    acc[m][n] = mfma16(aLo[m][0], S0.h[n], acc[m][n]);
                    acc[m][n] = mfma16(aHi[m][1], S1.h[n], acc[m][n]);
                    acc[m][n] = mfma16(aLo[m][1], S1.h[n], acc[m][n]);
                    acc[m][n] = mfma16(aHi[m][2], S2.h[n], acc[m][n]);
                    acc[m][n] = mfma16(aLo[m][2], S2.h[n], acc[m][n]);
                    acc[m][n] = mfma16(aHi[m][3], S3.h[n], acc[m][n]);
                    acc[m][n] = mfma16(aLo[m][3], S3.h[n], acc[m][n]);
                }
        }

        // ---- park per-wave partials (padded rows: conflict-free) ----
#pragma unroll
        for (int m = 0; m < 4; ++m)
#pragma unroll
            for (int n = 0; n < 4; ++n)
#pragma unroll
                for (int r = 0; r < 4; ++r)
                    red[wv * REDW + (m * 16 + kg * 4 + r) * 65 + n * 16 + col] = acc[m][n][r];
        __syncthreads();

        // ---- epilogue: 512 threads x 2 (ui,b) pairs (static unroll) ----
        {
#pragma unroll
            for (int hf = 0; hf < 2; ++hf) {
                const int ui = ui0 + hf * 8;
                float pre[4];
#pragma unroll
                for (int gi = 0; gi < 4; ++gi) {
                    const int row_loc = (ui >> 2) * 16 + gi * 4 + (ui & 3);
                    float s = bias_r[hf][gi];
#pragma unroll
                    for (int w8 = 0; w8 < 8; ++w8)
                        s += red[w8 * REDW + row_loc * 65 + b_ep];
                    pre[gi] = s;
                }
                float ig = 1.f / (1.f + expf(-pre[0]));
                float fg = 1.f / (1.f + expf(-pre[1]));
                float gg = tanhf(pre[2]);
                float og = 1.f / (1.f + expf(-pre[3]));
                float cs = hf ? c1 : c0;
                cs = fg * cs + ig * gg;
                if (hf) c1 = cs; else c0 = cs;
                float hv = og * tanhf(cs);
                hs_hi[b_ep * UPW + ui] = bf16rn(hv);
            }
        }
        __syncthreads();

        // ---- uniform tail (proven): coalesced h store by tid<64 ----
        if (tid < 64) {
            short8 v0 = *(const short8*)(hs_hi + (size_t)tid * UPW);
            short8 v1 = *(const short8*)(hs_hi + (size_t)tid * UPW + 8);
            ushort_t* dst = h_hi + (size_t)(t & 1) * (BATCH * HID)
                            + (size_t)tid * HID + u0;
            asm volatile("global_store_dwordx4 %0, %1, off sc0 sc1"
                         :: "v"(dst), "v"(v0) : "memory");
            asm volatile("global_store_dwordx4 %0, %1, off sc0 sc1"
                         :: "v"(dst + 8), "v"(v1) : "memory");
        }
        WAITVM(0);        // drain h stores wave-wide before the barrier
        __syncthreads();
        if (tid == 0)     // release first (ahead of FC issue in wave0)
            __hip_atomic_store(flags + wg, t + 1, __ATOMIC_RELAXED, __HIP_MEMORY_SCOPE_AGENT);
        // ---- FC partial (after release; off critical path) ----
        if (tid < 64) {
            float s = 0.f;
#pragma unroll
            for (int ui = 0; ui < UPW; ++ui)
                s += bf16f(hs_hi[tid * UPW + ui]) * wfcs[ui];
            atomicAdd(&out[(size_t)tid * T_STEPS + t], s);
        }
    }
}

// ---------------------------------------------------------------------------
extern "C" void kernel_launch(void* const* d_in, const int* in_sizes, int n_in,
                              void* d_out, int out_size, void* d_ws, size_t ws_size,
                              hipStream_t stream)
{
    const float* x   = (const float*)d_in[0];
    const float* Wih = (const float*)d_in[1];
    const float* Whh = (const float*)d_in[2];
    const float* bih = (const float*)d_in[3];
    const float* bhh = (const float*)d_in[4];
    const float* Wfc = (const float*)d_in[5];
    const float* bfc = (const float*)d_in[6];
    float* out = (float*)d_out;

    ushort_t* xhi  = (ushort_t*)d_ws;                         // 512*64*256
    ushort_t* xlo  = xhi + (size_t)T_STEPS * BATCH * IN;      // 512*64*256
    ushort_t* h_hi = xlo + (size_t)T_STEPS * BATCH * IN;      // 2*64*1024
    int*     flags = (int*)(h_hi + 2 * BATCH * HID);          // 256 ints

    (void)hipFuncSetAttribute((const void*)lstm_seq,
                              hipFuncAttributeMaxDynamicSharedMemorySize, LDS_BYTES);

    init_k<<<dim3((BATCH * T_STEPS + 255) / 256), dim3(256), 0, stream>>>(out, flags, bfc);
    xprep_k<<<dim3(T_STEPS), dim3(256), 0, stream>>>(x, xhi, xlo);
    lstm_seq<<<dim3(NWG), dim3(512), LDS_BYTES, stream>>>(
        Whh, Wih, bih, bhh, Wfc, xhi, xlo, h_hi, out, flags);
}

// Round 17
// 2364.156 us; speedup vs baseline: 3.2537x; 3.2537x over previous
//
#include <hip/hip_runtime.h>

#define T_STEPS 512
#define BATCH   64
#define HID     1024
#define IN      256
#define NWG     128
#define UPW     8             // hidden units per WG (M = 32 gate rows)
#define REDP    68            // red row pitch (2-way bank alias = free)
#define REDW    (32*REDP)     // floats per wave slice
#define LDS_FLOATS (8*REDW + 256 + 8)   // red + hs_hi(1024B) + wfcs
#define LDS_BYTES  (LDS_FLOATS * 4)

typedef float  f32x4  __attribute__((ext_vector_type(4)));
typedef short  short8 __attribute__((ext_vector_type(8)));
typedef unsigned short ushort_t;
typedef unsigned int   uint_t;

#define WAITVM(N) asm volatile("s_waitcnt vmcnt(" #N ")" ::: "memory")
#define SB0() __builtin_amdgcn_sched_barrier(0)

// ---------------------------------------------------------------------------
__device__ __forceinline__ ushort_t bf16rn(float f) {
    uint_t u = __builtin_bit_cast(uint_t, f);
    u += 0x7fff + ((u >> 16) & 1);
    return (ushort_t)(u >> 16);
}
__device__ __forceinline__ float bf16f(ushort_t h) {
    return __builtin_bit_cast(float, (uint_t)h << 16);
}
__device__ __forceinline__ void conv8(float4 a, float4 b, short8& hi, short8& lo) {
    float v[8] = {a.x, a.y, a.z, a.w, b.x, b.y, b.z, b.w};
#pragma unroll
    for (int j = 0; j < 8; ++j) {
        ushort_t h = bf16rn(v[j]);
        ushort_t l = bf16rn(v[j] - bf16f(h));
        hi[j] = (short)h; lo[j] = (short)l;
    }
}
__device__ __forceinline__ f32x4 mfma16(short8 a, short8 b, f32x4 c) {
    return __builtin_amdgcn_mfma_f32_16x16x32_bf16(a, b, c, 0, 0, 0);
}
// L1/L2-bypass 16B load; data valid only after s_waitcnt vmcnt(0) + sched_barrier.
__device__ __forceinline__ short8 load_coh16(const void* p) {
    short8 r;
    asm volatile("global_load_dwordx4 %0, %1, off sc0 sc1" : "=v"(r) : "v"(p));
    return r;
}

struct Frag4 { short8 h[4]; };

// tiled layout: one tile = [4 n][64 lane][8 k] ushorts; n-stride 1024 B.
__device__ __forceinline__ void issue_set(const char* base, Frag4& F) {
#pragma unroll
    for (int n = 0; n < 4; ++n)
        F.h[n] = load_coh16(base + n * 1024);
}

// ---------------------------------------------------------------------------
// out init (b_fc) + flag clear.  grid 128 x 256.
__global__ __launch_bounds__(256) void init_k(
    float* __restrict__ out, int* __restrict__ flags, const float* __restrict__ bfc)
{
    int i = blockIdx.x * 256 + threadIdx.x;
    if (i < BATCH * T_STEPS) out[i] = bfc[0];
    if (i < 256) flags[i] = 0;
}

// x[b][t][i] -> xhi/xlo tiled [t][kt=i>>5][n=b>>4][lane=((i>>3)&3)*16+(b&15)][j=i&7]
// grid 512 (t), block 256 (i).
__global__ __launch_bounds__(256) void xprep_k(
    const float* __restrict__ x, ushort_t* __restrict__ xhi, ushort_t* __restrict__ xlo)
{
    const int t = blockIdx.x, i = threadIdx.x;
    const int kt = i >> 5, kg = (i >> 3) & 3, j = i & 7;
    for (int b = 0; b < BATCH; ++b) {
        float v = x[((size_t)b * T_STEPS + t) * IN + i];
        ushort_t h = bf16rn(v);
        ushort_t l = bf16rn(v - bf16f(h));
        size_t o = (size_t)t * 16384 + kt * 2048 + (b >> 4) * 512
                 + (kg * 16 + (b & 15)) * 8 + j;
        xhi[o] = h; xlo[o] = l;
    }
}

// ---------------------------------------------------------------------------
// Persistent fused LSTM, MFMA split-bf16 weights/x, single-plane bf16 h,
// FRAGMENT-TILED transport layouts. grid 128, block 512 (8 waves).
// h plane = [32 kt][4 n][64 lane][8 k] bf16 (4096 B/tile): every consumer
// load instruction reads 1 KB fully contiguous (was 64 lines at stride 2048).
// Wave wv owns h k-tiles {4wv..4wv+3} (producers: WGs 16wv..16wv+15), spins
// only on its own 16 producer flags (R15-proven). Uniform tail (the only
// structure that ever passed): tid<64 h store (contiguous in tile layout)
// -> ALL waves WAITVM(0) -> bar -> tid0 release -> tid<64 FC atomicAdd.
// ---------------------------------------------------------------------------
__global__ __launch_bounds__(512, 2) void lstm_seq(
    const float* __restrict__ Whh, const float* __restrict__ Wih,
    const float* __restrict__ bih, const float* __restrict__ bhh,
    const float* __restrict__ Wfc,
    const ushort_t* __restrict__ xhi, const ushort_t* __restrict__ xlo,
    ushort_t* __restrict__ h_hi,  // [2][32][4][64][8] bf16 tiled
    float* __restrict__ out,      // [BATCH][T]
    int* __restrict__ flags)      // [NWG]
{
    extern __shared__ float smem[];
    float*    red   = smem;                               // [8][32][REDP]
    ushort_t* hs_hi = (ushort_t*)(smem + 8 * REDW);       // [64][8] ushort (1024 B)
    float*    wfcs  = smem + 8 * REDW + 256;              // [8]

    const int tid  = threadIdx.x;
    const int wg   = blockIdx.x;
    const int u0   = wg * UPW;
    const int lane = tid & 63;
    const int wv   = tid >> 6;        // wave 0..7
    const int col  = lane & 15;
    const int kg   = lane >> 4;       // 0..3

    // ---- one-time: A-fragments (weights, split bf16) into registers ----
    // h k-tiles: kt = 4*wv + i (i<4)  [contiguous per wave]; x k-tile: wv.
    short8 aHi[2][5], aLo[2][5];
    {
        const size_t growB = (size_t)(col >> 2) * HID + u0 + (col & 3);
#pragma unroll
        for (int m = 0; m < 2; ++m) {
            const size_t grow = growB + m * 4;
#pragma unroll
            for (int i = 0; i < 5; ++i) {
                const int k0 = (i < 4) ? (128 * wv + 32 * i + kg * 8)
                                       : (32 * wv + kg * 8);
                const float* wp = (i < 4) ? (Whh + grow * HID + k0)
                                          : (Wih + grow * IN + k0);
                float4 wa = *(const float4*)wp;
                float4 wb = *(const float4*)(wp + 4);
                conv8(wa, wb, aHi[m][i], aLo[m][i]);
            }
        }
    }
    if (tid < UPW) wfcs[tid] = Wfc[u0 + tid];

    const char* hhiB = (const char*)h_hi;
    const int pf = wv * 16 + col;                      // this wave's producer flag

    // epilogue constants: thread owns (ui = tid>>6, b = tid&63)
    const int ui_ep = tid >> 6;
    const int b_ep  = tid & 63;
    float bias_r[4];
#pragma unroll
    for (int gi = 0; gi < 4; ++gi)
        bias_r[gi] = bih[gi * HID + u0 + ui_ep] + bhh[gi * HID + u0 + ui_ep];

    // tail store address (tiled layout), constant per thread (tid<64, b=tid):
    // kt=wg>>2, kg=wg&3, n=b>>4, col=b&15, 8 units = 16 B chunk.
    const size_t hstore_off = (size_t)(wg >> 2) * 2048 + (size_t)(b_ep >> 4) * 512
                            + ((wg & 3) * 16 + (b_ep & 15)) * 8;   // in ushorts

    float c_state = 0.f;
    __syncthreads();

    for (int t = 0; t < T_STEPS; ++t) {
        f32x4 acc[2][4];
#pragma unroll
        for (int m = 0; m < 2; ++m)
#pragma unroll
            for (int n = 0; n < 4; ++n) acc[m][n] = (f32x4)0.f;

        // ---- x part (tiled, coalesced cached loads; pre-spin overlap) ----
        {
            const char* bx = (const char*)xhi + (size_t)t * 32768 + wv * 4096 + lane * 16;
            const char* bl = (const char*)xlo + (size_t)t * 32768 + wv * 4096 + lane * 16;
            short8 xh[4], xl[4];
#pragma unroll
            for (int n = 0; n < 4; ++n) {
                xh[n] = *(const short8*)(bx + n * 1024);
                xl[n] = *(const short8*)(bl + n * 1024);
            }
#pragma unroll
            for (int m = 0; m < 2; ++m)
#pragma unroll
                for (int n = 0; n < 4; ++n) {
                    acc[m][n] = mfma16(aHi[m][4], xh[n], acc[m][n]);
                    acc[m][n] = mfma16(aHi[m][4], xl[n], acc[m][n]);
                    acc[m][n] = mfma16(aLo[m][4], xh[n], acc[m][n]);
                }
        }

        // ---- h part: PER-WAVE spin on own 16 producers, then tiled loads ----
        if (t > 0) {
            for (;;) {
                int f = __hip_atomic_load(flags + pf, __ATOMIC_RELAXED, __HIP_MEMORY_SCOPE_AGENT);
                if (__all(f >= t)) break;
                __builtin_amdgcn_s_sleep(1);
            }
            SB0();

            const int buf = ((t - 1) & 1) * 131072;   // bytes per h buffer
            const char* bh = hhiB + buf + (4 * wv) * 4096 + lane * 16;
            Frag4 S0, S1, S2, S3;
            issue_set(bh +     0, S0);    // tile 4wv
            issue_set(bh +  4096, S1);    // tile 4wv+1
            issue_set(bh +  8192, S2);    // tile 4wv+2
            issue_set(bh + 12288, S3);    // tile 4wv+3
            WAITVM(0); SB0();     // all 16 landed; only now touch the frags
#pragma unroll
            for (int m = 0; m < 2; ++m)
#pragma unroll
                for (int n = 0; n < 4; ++n) {
                    acc[m][n] = mfma16(aHi[m][0], S0.h[n], acc[m][n]);
                    acc[m][n] = mfma16(aLo[m][0], S0.h[n], acc[m][n]);
                    acc[m][n] = mfma16(aHi[m][1], S1.h[n], acc[m][n]);
                    acc[m][n] = mfma16(aLo[m][1], S1.h[n], acc[m][n]);
                    acc[m][n] = mfma16(aHi[m][2], S2.h[n], acc[m][n]);
                    acc[m][n] = mfma16(aLo[m][2], S2.h[n], acc[m][n]);
                    acc[m][n] = mfma16(aHi[m][3], S3.h[n], acc[m][n]);
                    acc[m][n] = mfma16(aLo[m][3], S3.h[n], acc[m][n]);
                }
        }

        // ---- park per-wave partials (pitch 68: 2-way alias = free) ----
#pragma unroll
        for (int m = 0; m < 2; ++m)
#pragma unroll
            for (int n = 0; n < 4; ++n)
#pragma unroll
                for (int r = 0; r < 4; ++r)
                    red[wv * REDW + (m * 16 + kg * 4 + r) * REDP + n * 16 + col] = acc[m][n][r];
        __syncthreads();

        // ---- epilogue: all 512 threads, one (ui,b) each ----
        {
            float pre[4];
#pragma unroll
            for (int gi = 0; gi < 4; ++gi) {
                const int row_loc = (ui_ep >> 2) * 16 + gi * 4 + (ui_ep & 3);
                float s = bias_r[gi];
#pragma unroll
                for (int w8 = 0; w8 < 8; ++w8)
                    s += red[w8 * REDW + row_loc * REDP + b_ep];
                pre[gi] = s;
            }
            float ig = 1.f / (1.f + expf(-pre[0]));
            float fg = 1.f / (1.f + expf(-pre[1]));
            float gg = tanhf(pre[2]);
            float og = 1.f / (1.f + expf(-pre[3]));
            c_state = fg * c_state + ig * gg;
            float hv = og * tanhf(c_state);
            hs_hi[b_ep * UPW + ui_ep] = bf16rn(hv);
        }
        __syncthreads();

        // ---- uniform tail (proven): tiled coalesced h store by tid<64 ----
        if (tid < 64) {
            short8 v = *(const short8*)(hs_hi + (size_t)tid * UPW);
            ushort_t* dst = h_hi + (size_t)(t & 1) * 65536 + hstore_off;
            asm volatile("global_store_dwordx4 %0, %1, off sc0 sc1"
                         :: "v"(dst), "v"(v) : "memory");
        }
        WAITVM(0);        // drain h stores wave-wide before the barrier
        __syncthreads();
        if (tid == 0)     // release first (ahead of FC issue in wave0)
            __hip_atomic_store(flags + wg, t + 1, __ATOMIC_RELAXED, __HIP_MEMORY_SCOPE_AGENT);
        // ---- FC partial (after release; off critical path) ----
        if (tid < 64) {
            float s = 0.f;
#pragma unroll
            for (int ui = 0; ui < UPW; ++ui)
                s += bf16f(hs_hi[tid * UPW + ui]) * wfcs[ui];
            atomicAdd(&out[(size_t)tid * T_STEPS + t], s);
        }
    }
}

// ---------------------------------------------------------------------------
extern "C" void kernel_launch(void* const* d_in, const int* in_sizes, int n_in,
                              void* d_out, int out_size, void* d_ws, size_t ws_size,
                              hipStream_t stream)
{
    const float* x   = (const float*)d_in[0];
    const float* Wih = (const float*)d_in[1];
    const float* Whh = (const float*)d_in[2];
    const float* bih = (const float*)d_in[3];
    const float* bhh = (const float*)d_in[4];
    const float* Wfc = (const float*)d_in[5];
    const float* bfc = (const float*)d_in[6];
    float* out = (float*)d_out;

    ushort_t* xhi  = (ushort_t*)d_ws;                         // 512*64*256
    ushort_t* xlo  = xhi + (size_t)T_STEPS * BATCH * IN;      // 512*64*256
    ushort_t* h_hi = xlo + (size_t)T_STEPS * BATCH * IN;      // 2*64*1024
    int*     flags = (int*)(h_hi + 2 * BATCH * HID);          // 256 ints

    (void)hipFuncSetAttribute((const void*)lstm_seq,
                              hipFuncAttributeMaxDynamicSharedMemorySize, LDS_BYTES);

    init_k<<<dim3((BATCH * T_STEPS + 255) / 256), dim3(256), 0, stream>>>(out, flags, bfc);
    xprep_k<<<dim3(T_STEPS), dim3(256), 0, stream>>>(x, xhi, xlo);
    lstm_seq<<<dim3(NWG), dim3(512), LDS_BYTES, stream>>>(
        Whh, Wih, bih, bhh, Wfc, xhi, xlo, h_hi, out, flags);
}

// Round 18
// 2346.143 us; speedup vs baseline: 3.2787x; 1.0077x over previous
//
#include <hip/hip_runtime.h>

#define T_STEPS 512
#define BATCH   64
#define HID     1024
#define IN      256
#define NWG     128
#define UPW     8             // hidden units per WG (M = 32 gate rows)
#define REDP    68            // red row pitch (2-way bank alias = free)
#define REDW    (32*REDP)     // floats per wave slice
#define LDS_FLOATS (8*REDW + 256 + 8)   // red + hs_hi(1024B) + wfcs
#define LDS_BYTES  (LDS_FLOATS * 4)

typedef float  f32x4  __attribute__((ext_vector_type(4)));
typedef short  short8 __attribute__((ext_vector_type(8)));
typedef unsigned short ushort_t;
typedef unsigned int   uint_t;

#define WAITVM(N) asm volatile("s_waitcnt vmcnt(" #N ")" ::: "memory")
#define SB0() __builtin_amdgcn_sched_barrier(0)

// ---------------------------------------------------------------------------
__device__ __forceinline__ ushort_t bf16rn(float f) {
    uint_t u = __builtin_bit_cast(uint_t, f);
    u += 0x7fff + ((u >> 16) & 1);
    return (ushort_t)(u >> 16);
}
__device__ __forceinline__ float bf16f(ushort_t h) {
    return __builtin_bit_cast(float, (uint_t)h << 16);
}
__device__ __forceinline__ void conv8(float4 a, float4 b, short8& hi, short8& lo) {
    float v[8] = {a.x, a.y, a.z, a.w, b.x, b.y, b.z, b.w};
#pragma unroll
    for (int j = 0; j < 8; ++j) {
        ushort_t h = bf16rn(v[j]);
        ushort_t l = bf16rn(v[j] - bf16f(h));
        hi[j] = (short)h; lo[j] = (short)l;
    }
}
__device__ __forceinline__ f32x4 mfma16(short8 a, short8 b, f32x4 c) {
    return __builtin_amdgcn_mfma_f32_16x16x32_bf16(a, b, c, 0, 0, 0);
}
// L1/L2-bypass 16B load; data valid only after s_waitcnt vmcnt(0) + sched_barrier.
__device__ __forceinline__ short8 load_coh16(const void* p) {
    short8 r;
    asm volatile("global_load_dwordx4 %0, %1, off sc0 sc1" : "=v"(r) : "v"(p));
    return r;
}
__device__ __forceinline__ int load_coh_i32(const void* p) {
    int r;
    asm volatile("global_load_dword %0, %1, off sc0 sc1" : "=v"(r) : "v"(p));
    return r;
}

struct Frag4 { short8 h[4]; };

// tiled layout: one tile = [4 n][64 lane][8 k] ushorts; n-stride 1024 B.
__device__ __forceinline__ void issue_set(const char* base, Frag4& F) {
#pragma unroll
    for (int n = 0; n < 4; ++n)
        F.h[n] = load_coh16(base + n * 1024);
}

// ---------------------------------------------------------------------------
// out init (b_fc) + flag clear.  grid 128 x 256.
__global__ __launch_bounds__(256) void init_k(
    float* __restrict__ out, int* __restrict__ flags, const float* __restrict__ bfc)
{
    int i = blockIdx.x * 256 + threadIdx.x;
    if (i < BATCH * T_STEPS) out[i] = bfc[0];
    if (i < 256) flags[i] = 0;
}

// x[b][t][i] -> xhi/xlo tiled [t][kt=i>>5][n=b>>4][lane=((i>>3)&3)*16+(b&15)][j=i&7]
// grid 512 (t), block 256 (i).
__global__ __launch_bounds__(256) void xprep_k(
    const float* __restrict__ x, ushort_t* __restrict__ xhi, ushort_t* __restrict__ xlo)
{
    const int t = blockIdx.x, i = threadIdx.x;
    const int kt = i >> 5, kg = (i >> 3) & 3, j = i & 7;
    for (int b = 0; b < BATCH; ++b) {
        float v = x[((size_t)b * T_STEPS + t) * IN + i];
        ushort_t h = bf16rn(v);
        ushort_t l = bf16rn(v - bf16f(h));
        size_t o = (size_t)t * 16384 + kt * 2048 + (b >> 4) * 512
                 + (kg * 16 + (b & 15)) * 8 + j;
        xhi[o] = h; xlo[o] = l;
    }
}

// ---------------------------------------------------------------------------
// Persistent fused LSTM, MFMA split-bf16 weights/x, single-plane bf16 h,
// fragment-tiled transport, SPECULATIVE fused flag+data load.
// grid 128, block 512 (8 waves). Wave wv owns h k-tiles {4wv..4wv+3}
// (producers: WGs 16wv..16wv+15). Steady state: issue flag load + all 16
// tiled h loads together, single vmcnt(0) drain, check flag — one LIC round
// trip instead of two. Seqlock safety: producer drains h stores (full ACK)
// BEFORE its flag store, so a fresh flag implies data arrived >=1 round trip
// before our loads. Stale flag (rare): classic spin then RE-ISSUE all data
// loads (R17 path). Consumption strictly drain-then-consume; uniform tail.
// ---------------------------------------------------------------------------
__global__ __launch_bounds__(512, 2) void lstm_seq(
    const float* __restrict__ Whh, const float* __restrict__ Wih,
    const float* __restrict__ bih, const float* __restrict__ bhh,
    const float* __restrict__ Wfc,
    const ushort_t* __restrict__ xhi, const ushort_t* __restrict__ xlo,
    ushort_t* __restrict__ h_hi,  // [2][32][4][64][8] bf16 tiled
    float* __restrict__ out,      // [BATCH][T]
    int* __restrict__ flags)      // [NWG]
{
    extern __shared__ float smem[];
    float*    red   = smem;                               // [8][32][REDP]
    ushort_t* hs_hi = (ushort_t*)(smem + 8 * REDW);       // [64][8] ushort (1024 B)
    float*    wfcs  = smem + 8 * REDW + 256;              // [8]

    const int tid  = threadIdx.x;
    const int wg   = blockIdx.x;
    const int u0   = wg * UPW;
    const int lane = tid & 63;
    const int wv   = tid >> 6;        // wave 0..7
    const int col  = lane & 15;
    const int kg   = lane >> 4;       // 0..3

    // ---- one-time: A-fragments (weights, split bf16) into registers ----
    // h k-tiles: kt = 4*wv + i (i<4)  [contiguous per wave]; x k-tile: wv.
    short8 aHi[2][5], aLo[2][5];
    {
        const size_t growB = (size_t)(col >> 2) * HID + u0 + (col & 3);
#pragma unroll
        for (int m = 0; m < 2; ++m) {
            const size_t grow = growB + m * 4;
#pragma unroll
            for (int i = 0; i < 5; ++i) {
                const int k0 = (i < 4) ? (128 * wv + 32 * i + kg * 8)
                                       : (32 * wv + kg * 8);
                const float* wp = (i < 4) ? (Whh + grow * HID + k0)
                                          : (Wih + grow * IN + k0);
                float4 wa = *(const float4*)wp;
                float4 wb = *(const float4*)(wp + 4);
                conv8(wa, wb, aHi[m][i], aLo[m][i]);
            }
        }
    }
    if (tid < UPW) wfcs[tid] = Wfc[u0 + tid];

    const char* hhiB = (const char*)h_hi;
    const int pf = wv * 16 + col;                      // this wave's producer flag

    // epilogue constants: thread owns (ui = tid>>6, b = tid&63)
    const int ui_ep = tid >> 6;
    const int b_ep  = tid & 63;
    float bias_r[4];
#pragma unroll
    for (int gi = 0; gi < 4; ++gi)
        bias_r[gi] = bih[gi * HID + u0 + ui_ep] + bhh[gi * HID + u0 + ui_ep];

    // tail store address (tiled layout), constant per thread (tid<64, b=tid):
    const size_t hstore_off = (size_t)(wg >> 2) * 2048 + (size_t)(b_ep >> 4) * 512
                            + ((wg & 3) * 16 + (b_ep & 15)) * 8;   // in ushorts

    float c_state = 0.f;
    __syncthreads();

    for (int t = 0; t < T_STEPS; ++t) {
        f32x4 acc[2][4];
#pragma unroll
        for (int m = 0; m < 2; ++m)
#pragma unroll
            for (int n = 0; n < 4; ++n) acc[m][n] = (f32x4)0.f;

        // ---- x part (tiled, coalesced cached loads; pre-spin overlap) ----
        {
            const char* bx = (const char*)xhi + (size_t)t * 32768 + wv * 4096 + lane * 16;
            const char* bl = (const char*)xlo + (size_t)t * 32768 + wv * 4096 + lane * 16;
            short8 xh[4], xl[4];
#pragma unroll
            for (int n = 0; n < 4; ++n) {
                xh[n] = *(const short8*)(bx + n * 1024);
                xl[n] = *(const short8*)(bl + n * 1024);
            }
#pragma unroll
            for (int m = 0; m < 2; ++m)
#pragma unroll
                for (int n = 0; n < 4; ++n) {
                    acc[m][n] = mfma16(aHi[m][4], xh[n], acc[m][n]);
                    acc[m][n] = mfma16(aHi[m][4], xl[n], acc[m][n]);
                    acc[m][n] = mfma16(aLo[m][4], xh[n], acc[m][n]);
                }
        }

        // ---- h part: speculative fused flag+data load (1 round trip) ----
        if (t > 0) {
            const int buf = ((t - 1) & 1) * 131072;   // bytes per h buffer
            const char* bh = hhiB + buf + (4 * wv) * 4096 + lane * 16;
            Frag4 S0, S1, S2, S3;
            int f = load_coh_i32(flags + pf);    // flag first (safer ordering)
            issue_set(bh +     0, S0);
            issue_set(bh +  4096, S1);
            issue_set(bh +  8192, S2);
            issue_set(bh + 12288, S3);
            WAITVM(0); SB0();
            if (!__all(f >= t)) {
                // rare: producers not done — classic spin, then RE-issue data
                for (;;) {
                    int f2 = __hip_atomic_load(flags + pf, __ATOMIC_RELAXED, __HIP_MEMORY_SCOPE_AGENT);
                    if (__all(f2 >= t)) break;
                    __builtin_amdgcn_s_sleep(1);
                }
                SB0();
                issue_set(bh +     0, S0);
                issue_set(bh +  4096, S1);
                issue_set(bh +  8192, S2);
                issue_set(bh + 12288, S3);
                WAITVM(0); SB0();
            }
#pragma unroll
            for (int m = 0; m < 2; ++m)
#pragma unroll
                for (int n = 0; n < 4; ++n) {
                    acc[m][n] = mfma16(aHi[m][0], S0.h[n], acc[m][n]);
                    acc[m][n] = mfma16(aLo[m][0], S0.h[n], acc[m][n]);
                    acc[m][n] = mfma16(aHi[m][1], S1.h[n], acc[m][n]);
                    acc[m][n] = mfma16(aLo[m][1], S1.h[n], acc[m][n]);
                    acc[m][n] = mfma16(aHi[m][2], S2.h[n], acc[m][n]);
                    acc[m][n] = mfma16(aLo[m][2], S2.h[n], acc[m][n]);
                    acc[m][n] = mfma16(aHi[m][3], S3.h[n], acc[m][n]);
                    acc[m][n] = mfma16(aLo[m][3], S3.h[n], acc[m][n]);
                }
        }

        // ---- park per-wave partials (pitch 68: 2-way alias = free) ----
#pragma unroll
        for (int m = 0; m < 2; ++m)
#pragma unroll
            for (int n = 0; n < 4; ++n)
#pragma unroll
                for (int r = 0; r < 4; ++r)
                    red[wv * REDW + (m * 16 + kg * 4 + r) * REDP + n * 16 + col] = acc[m][n][r];
        __syncthreads();

        // ---- epilogue: all 512 threads, one (ui,b) each ----
        {
            float pre[4];
#pragma unroll
            for (int gi = 0; gi < 4; ++gi) {
                const int row_loc = (ui_ep >> 2) * 16 + gi * 4 + (ui_ep & 3);
                float s = bias_r[gi];
#pragma unroll
                for (int w8 = 0; w8 < 8; ++w8)
                    s += red[w8 * REDW + row_loc * REDP + b_ep];
                pre[gi] = s;
            }
            float ig = 1.f / (1.f + expf(-pre[0]));
            float fg = 1.f / (1.f + expf(-pre[1]));
            float gg = tanhf(pre[2]);
            float og = 1.f / (1.f + expf(-pre[3]));
            c_state = fg * c_state + ig * gg;
            float hv = og * tanhf(c_state);
            hs_hi[b_ep * UPW + ui_ep] = bf16rn(hv);
        }
        __syncthreads();

        // ---- uniform tail (proven): tiled coalesced h store by tid<64 ----
        if (tid < 64) {
            short8 v = *(const short8*)(hs_hi + (size_t)tid * UPW);
            ushort_t* dst = h_hi + (size_t)(t & 1) * 65536 + hstore_off;
            asm volatile("global_store_dwordx4 %0, %1, off sc0 sc1"
                         :: "v"(dst), "v"(v) : "memory");
        }
        WAITVM(0);        // drain h stores wave-wide before the barrier
        __syncthreads();
        if (tid == 0)     // release first (ahead of FC issue in wave0)
            __hip_atomic_store(flags + wg, t + 1, __ATOMIC_RELAXED, __HIP_MEMORY_SCOPE_AGENT);
        // ---- FC partial (after release; off critical path) ----
        if (tid < 64) {
            float s = 0.f;
#pragma unroll
            for (int ui = 0; ui < UPW; ++ui)
                s += bf16f(hs_hi[tid * UPW + ui]) * wfcs[ui];
            atomicAdd(&out[(size_t)tid * T_STEPS + t], s);
        }
    }
}

// ---------------------------------------------------------------------------
extern "C" void kernel_launch(void* const* d_in, const int* in_sizes, int n_in,
                              void* d_out, int out_size, void* d_ws, size_t ws_size,
                              hipStream_t stream)
{
    const float* x   = (const float*)d_in[0];
    const float* Wih = (const float*)d_in[1];
    const float* Whh = (const float*)d_in[2];
    const float* bih = (const float*)d_in[3];
    const float* bhh = (const float*)d_in[4];
    const float* Wfc = (const float*)d_in[5];
    const float* bfc = (const float*)d_in[6];
    float* out = (float*)d_out;

    ushort_t* xhi  = (ushort_t*)d_ws;                         // 512*64*256
    ushort_t* xlo  = xhi + (size_t)T_STEPS * BATCH * IN;      // 512*64*256
    ushort_t* h_hi = xlo + (size_t)T_STEPS * BATCH * IN;      // 2*64*1024
    int*     flags = (int*)(h_hi + 2 * BATCH * HID);          // 256 ints

    (void)hipFuncSetAttribute((const void*)lstm_seq,
                              hipFuncAttributeMaxDynamicSharedMemorySize, LDS_BYTES);

    init_k<<<dim3((BATCH * T_STEPS + 255) / 256), dim3(256), 0, stream>>>(out, flags, bfc);
    xprep_k<<<dim3(T_STEPS), dim3(256), 0, stream>>>(x, xhi, xlo);
    lstm_seq<<<dim3(NWG), dim3(512), LDS_BYTES, stream>>>(
        Whh, Wih, bih, bhh, Wfc, xhi, xlo, h_hi, out, flags);
}

// Round 19
// 2261.730 us; speedup vs baseline: 3.4011x; 1.0373x over previous
//
#include <hip/hip_runtime.h>

#define T_STEPS 512
#define BATCH   64
#define HID     1024
#define IN      256
#define NWG     128
#define UPW     8             // hidden units per WG (M = 32 gate rows)
#define REDP    68            // red row pitch (2-way bank alias = free)
#define REDW    (32*REDP)     // floats per wave slice
#define LDS_FLOATS (8*REDW + 256 + 8)   // red + hs_hi(1024B) + wfcs
#define LDS_BYTES  (LDS_FLOATS * 4)

typedef float  f32x4  __attribute__((ext_vector_type(4)));
typedef short  short8 __attribute__((ext_vector_type(8)));
typedef unsigned short ushort_t;
typedef unsigned int   uint_t;

#define WAITVM(N) asm volatile("s_waitcnt vmcnt(" #N ")" ::: "memory")
#define SB0() __builtin_amdgcn_sched_barrier(0)

// ---------------------------------------------------------------------------
__device__ __forceinline__ ushort_t bf16rn(float f) {
    uint_t u = __builtin_bit_cast(uint_t, f);
    u += 0x7fff + ((u >> 16) & 1);
    return (ushort_t)(u >> 16);
}
__device__ __forceinline__ float bf16f(ushort_t h) {
    return __builtin_bit_cast(float, (uint_t)h << 16);
}
__device__ __forceinline__ void conv8(float4 a, float4 b, short8& hi, short8& lo) {
    float v[8] = {a.x, a.y, a.z, a.w, b.x, b.y, b.z, b.w};
#pragma unroll
    for (int j = 0; j < 8; ++j) {
        ushort_t h = bf16rn(v[j]);
        ushort_t l = bf16rn(v[j] - bf16f(h));
        hi[j] = (short)h; lo[j] = (short)l;
    }
}
__device__ __forceinline__ f32x4 mfma16(short8 a, short8 b, f32x4 c) {
    return __builtin_amdgcn_mfma_f32_16x16x32_bf16(a, b, c, 0, 0, 0);
}
// fast gates: single v_exp_f32 path (saturates correctly at +/-inf)
__device__ __forceinline__ float fsigmoid(float x) {
    return 1.f / (1.f + __expf(-x));
}
__device__ __forceinline__ float ftanh(float x) {
    return 1.f - 2.f / (__expf(2.f * x) + 1.f);
}
// L1/L2-bypass 16B load; data valid only after s_waitcnt vmcnt(0) + sched_barrier.
__device__ __forceinline__ short8 load_coh16(const void* p) {
    short8 r;
    asm volatile("global_load_dwordx4 %0, %1, off sc0 sc1" : "=v"(r) : "v"(p));
    return r;
}
__device__ __forceinline__ int load_coh_i32(const void* p) {
    int r;
    asm volatile("global_load_dword %0, %1, off sc0 sc1" : "=v"(r) : "v"(p));
    return r;
}

struct Frag4 { short8 h[4]; };

// tiled layout: one tile = [4 n][64 lane][8 k] ushorts; n-stride 1024 B.
__device__ __forceinline__ void issue_set(const char* base, Frag4& F) {
#pragma unroll
    for (int n = 0; n < 4; ++n)
        F.h[n] = load_coh16(base + n * 1024);
}

// ---------------------------------------------------------------------------
// out init (b_fc) + flag clear.  grid 128 x 256.
__global__ __launch_bounds__(256) void init_k(
    float* __restrict__ out, int* __restrict__ flags, const float* __restrict__ bfc)
{
    int i = blockIdx.x * 256 + threadIdx.x;
    if (i < BATCH * T_STEPS) out[i] = bfc[0];
    if (i < 256) flags[i] = 0;
}

// x[b][t][i] -> xhi/xlo tiled [t][kt=i>>5][n=b>>4][lane=((i>>3)&3)*16+(b&15)][j=i&7]
// grid 512 (t), block 256 (i).
__global__ __launch_bounds__(256) void xprep_k(
    const float* __restrict__ x, ushort_t* __restrict__ xhi, ushort_t* __restrict__ xlo)
{
    const int t = blockIdx.x, i = threadIdx.x;
    const int kt = i >> 5, kg = (i >> 3) & 3, j = i & 7;
    for (int b = 0; b < BATCH; ++b) {
        float v = x[((size_t)b * T_STEPS + t) * IN + i];
        ushort_t h = bf16rn(v);
        ushort_t l = bf16rn(v - bf16f(h));
        size_t o = (size_t)t * 16384 + kt * 2048 + (b >> 4) * 512
                 + (kg * 16 + (b & 15)) * 8 + j;
        xhi[o] = h; xlo[o] = l;
    }
}

// ---------------------------------------------------------------------------
// Persistent fused LSTM, MFMA split-bf16 weights/x, single-plane bf16 h,
// fragment-tiled transport, speculative fused flag+data load, fast gates.
// grid 128, block 512 (8 waves). Wave wv owns h k-tiles {4wv..4wv+3}
// (producers: WGs 16wv..16wv+15). Uniform tail (the only structure that
// ever passed; divergent tails NaN'd 4x). Drain-then-consume everywhere.
// ---------------------------------------------------------------------------
__global__ __launch_bounds__(512, 2) void lstm_seq(
    const float* __restrict__ Whh, const float* __restrict__ Wih,
    const float* __restrict__ bih, const float* __restrict__ bhh,
    const float* __restrict__ Wfc,
    const ushort_t* __restrict__ xhi, const ushort_t* __restrict__ xlo,
    ushort_t* __restrict__ h_hi,  // [2][32][4][64][8] bf16 tiled
    float* __restrict__ out,      // [BATCH][T]
    int* __restrict__ flags)      // [NWG]
{
    extern __shared__ float smem[];
    float*    red   = smem;                               // [8][32][REDP]
    ushort_t* hs_hi = (ushort_t*)(smem + 8 * REDW);       // [64][8] ushort (1024 B)
    float*    wfcs  = smem + 8 * REDW + 256;              // [8]

    const int tid  = threadIdx.x;
    const int wg   = blockIdx.x;
    const int u0   = wg * UPW;
    const int lane = tid & 63;
    const int wv   = tid >> 6;        // wave 0..7
    const int col  = lane & 15;
    const int kg   = lane >> 4;       // 0..3

    // ---- one-time: A-fragments (weights, split bf16) into registers ----
    // h k-tiles: kt = 4*wv + i (i<4)  [contiguous per wave]; x k-tile: wv.
    short8 aHi[2][5], aLo[2][5];
    {
        const size_t growB = (size_t)(col >> 2) * HID + u0 + (col & 3);
#pragma unroll
        for (int m = 0; m < 2; ++m) {
            const size_t grow = growB + m * 4;
#pragma unroll
            for (int i = 0; i < 5; ++i) {
                const int k0 = (i < 4) ? (128 * wv + 32 * i + kg * 8)
                                       : (32 * wv + kg * 8);
                const float* wp = (i < 4) ? (Whh + grow * HID + k0)
                                          : (Wih + grow * IN + k0);
                float4 wa = *(const float4*)wp;
                float4 wb = *(const float4*)(wp + 4);
                conv8(wa, wb, aHi[m][i], aLo[m][i]);
            }
        }
    }
    if (tid < UPW) wfcs[tid] = Wfc[u0 + tid];

    const char* hhiB = (const char*)h_hi;
    const int pf = wv * 16 + col;                      // this wave's producer flag

    // epilogue constants: thread owns (ui = tid>>6, b = tid&63)
    const int ui_ep = tid >> 6;
    const int b_ep  = tid & 63;
    float bias_r[4];
#pragma unroll
    for (int gi = 0; gi < 4; ++gi)
        bias_r[gi] = bih[gi * HID + u0 + ui_ep] + bhh[gi * HID + u0 + ui_ep];

    // tail store address (tiled layout), constant per thread (tid<64, b=tid):
    const size_t hstore_off = (size_t)(wg >> 2) * 2048 + (size_t)(b_ep >> 4) * 512
                            + ((wg & 3) * 16 + (b_ep & 15)) * 8;   // in ushorts

    float c_state = 0.f;
    __syncthreads();

    for (int t = 0; t < T_STEPS; ++t) {
        f32x4 acc[2][4];

        // ---- x part (tiled, coalesced cached loads; acc init fused) ----
        {
            const char* bx = (const char*)xhi + (size_t)t * 32768 + wv * 4096 + lane * 16;
            const char* bl = (const char*)xlo + (size_t)t * 32768 + wv * 4096 + lane * 16;
            short8 xh[4], xl[4];
#pragma unroll
            for (int n = 0; n < 4; ++n) {
                xh[n] = *(const short8*)(bx + n * 1024);
                xl[n] = *(const short8*)(bl + n * 1024);
            }
#pragma unroll
            for (int m = 0; m < 2; ++m)
#pragma unroll
                for (int n = 0; n < 4; ++n) {
                    acc[m][n] = mfma16(aHi[m][4], xh[n], (f32x4)0.f);
                    acc[m][n] = mfma16(aHi[m][4], xl[n], acc[m][n]);
                    acc[m][n] = mfma16(aLo[m][4], xh[n], acc[m][n]);
                }
        }

        // ---- h part: speculative fused flag+data load (1 round trip) ----
        if (t > 0) {
            const int buf = ((t - 1) & 1) * 131072;   // bytes per h buffer
            const char* bh = hhiB + buf + (4 * wv) * 4096 + lane * 16;
            Frag4 S0, S1, S2, S3;
            int f = load_coh_i32(flags + pf);    // flag first (safer ordering)
            issue_set(bh +     0, S0);
            issue_set(bh +  4096, S1);
            issue_set(bh +  8192, S2);
            issue_set(bh + 12288, S3);
            WAITVM(0); SB0();
            if (!__all(f >= t)) {
                // rare: producers not done — classic spin, then RE-issue data
                for (;;) {
                    int f2 = __hip_atomic_load(flags + pf, __ATOMIC_RELAXED, __HIP_MEMORY_SCOPE_AGENT);
                    if (__all(f2 >= t)) break;
                    __builtin_amdgcn_s_sleep(1);
                }
                SB0();
                issue_set(bh +     0, S0);
                issue_set(bh +  4096, S1);
                issue_set(bh +  8192, S2);
                issue_set(bh + 12288, S3);
                WAITVM(0); SB0();
            }
#pragma unroll
            for (int m = 0; m < 2; ++m)
#pragma unroll
                for (int n = 0; n < 4; ++n) {
                    acc[m][n] = mfma16(aHi[m][0], S0.h[n], acc[m][n]);
                    acc[m][n] = mfma16(aLo[m][0], S0.h[n], acc[m][n]);
                    acc[m][n] = mfma16(aHi[m][1], S1.h[n], acc[m][n]);
                    acc[m][n] = mfma16(aLo[m][1], S1.h[n], acc[m][n]);
                    acc[m][n] = mfma16(aHi[m][2], S2.h[n], acc[m][n]);
                    acc[m][n] = mfma16(aLo[m][2], S2.h[n], acc[m][n]);
                    acc[m][n] = mfma16(aHi[m][3], S3.h[n], acc[m][n]);
                    acc[m][n] = mfma16(aLo[m][3], S3.h[n], acc[m][n]);
                }
        }

        // ---- park per-wave partials (pitch 68: 2-way alias = free) ----
#pragma unroll
        for (int m = 0; m < 2; ++m)
#pragma unroll
            for (int n = 0; n < 4; ++n)
#pragma unroll
                for (int r = 0; r < 4; ++r)
                    red[wv * REDW + (m * 16 + kg * 4 + r) * REDP + n * 16 + col] = acc[m][n][r];
        __syncthreads();

        // ---- epilogue: all 512 threads, one (ui,b) each; fast gates ----
        {
            float pre[4];
#pragma unroll
            for (int gi = 0; gi < 4; ++gi) {
                const int row_loc = (ui_ep >> 2) * 16 + gi * 4 + (ui_ep & 3);
                float s = bias_r[gi];
#pragma unroll
                for (int w8 = 0; w8 < 8; ++w8)
                    s += red[w8 * REDW + row_loc * REDP + b_ep];
                pre[gi] = s;
            }
            float ig = fsigmoid(pre[0]);
            float fg = fsigmoid(pre[1]);
            float gg = ftanh(pre[2]);
            float og = fsigmoid(pre[3]);
            c_state = fg * c_state + ig * gg;
            float hv = og * ftanh(c_state);
            hs_hi[b_ep * UPW + ui_ep] = bf16rn(hv);
        }
        __syncthreads();

        // ---- uniform tail (proven): tiled coalesced h store by tid<64 ----
        if (tid < 64) {
            short8 v = *(const short8*)(hs_hi + (size_t)tid * UPW);
            ushort_t* dst = h_hi + (size_t)(t & 1) * 65536 + hstore_off;
            asm volatile("global_store_dwordx4 %0, %1, off sc0 sc1"
                         :: "v"(dst), "v"(v) : "memory");
        }
        WAITVM(0);        // drain h stores wave-wide before the barrier
        __syncthreads();
        if (tid == 0)     // release first (ahead of FC issue in wave0)
            __hip_atomic_store(flags + wg, t + 1, __ATOMIC_RELAXED, __HIP_MEMORY_SCOPE_AGENT);
        // ---- FC partial (after release; off critical path) ----
        if (tid < 64) {
            float s = 0.f;
#pragma unroll
            for (int ui = 0; ui < UPW; ++ui)
                s += bf16f(hs_hi[tid * UPW + ui]) * wfcs[ui];
            atomicAdd(&out[(size_t)tid * T_STEPS + t], s);
        }
    }
}

// ---------------------------------------------------------------------------
extern "C" void kernel_launch(void* const* d_in, const int* in_sizes, int n_in,
                              void* d_out, int out_size, void* d_ws, size_t ws_size,
                              hipStream_t stream)
{
    const float* x   = (const float*)d_in[0];
    const float* Wih = (const float*)d_in[1];
    const float* Whh = (const float*)d_in[2];
    const float* bih = (const float*)d_in[3];
    const float* bhh = (const float*)d_in[4];
    const float* Wfc = (const float*)d_in[5];
    const float* bfc = (const float*)d_in[6];
    float* out = (float*)d_out;

    ushort_t* xhi  = (ushort_t*)d_ws;                         // 512*64*256
    ushort_t* xlo  = xhi + (size_t)T_STEPS * BATCH * IN;      // 512*64*256
    ushort_t* h_hi = xlo + (size_t)T_STEPS * BATCH * IN;      // 2*64*1024
    int*     flags = (int*)(h_hi + 2 * BATCH * HID);          // 256 ints

    (void)hipFuncSetAttribute((const void*)lstm_seq,
                              hipFuncAttributeMaxDynamicSharedMemorySize, LDS_BYTES);

    init_k<<<dim3((BATCH * T_STEPS + 255) / 256), dim3(256), 0, stream>>>(out, flags, bfc);
    xprep_k<<<dim3(T_STEPS), dim3(256), 0, stream>>>(x, xhi, xlo);
    lstm_seq<<<dim3(NWG), dim3(512), LDS_BYTES, stream>>>(
        Whh, Wih, bih, bhh, Wfc, xhi, xlo, h_hi, out, flags);
}